// Round 1
// baseline (604.321 us; speedup 1.0000x reference)
//
#include <hip/hip_runtime.h>
#include <stdint.h>

typedef float f32x4 __attribute__((ext_vector_type(4)));

// One WAVE per 32-bit word (grid-stride). Lane l's chunk k is the float4 at
// word_base + k*256 + l*4 floats, so each load/store instruction is a
// contiguous, aligned 1 KiB across the 64 lanes, and chunk k == byte pos k.
// Byte index extraction uses __ballot (exactly one 1.0 per 256-float chunk):
// no LDS, no __syncthreads, no shuffle chains — the word arithmetic is SALU.
__global__ __launch_bounds__(256, 8) void vm_kernel(
    const float* __restrict__ a_bytes,
    const float* __restrict__ b_bytes,
    float* __restrict__ out,
    int n_words)
{
    const int lane   = threadIdx.x & 63;
    const int wave   = blockIdx.x * (blockDim.x >> 6) + (threadIdx.x >> 6);
    const int nwaves = gridDim.x * (blockDim.x >> 6);

    for (int w = wave; w < n_words; w += nwaves) {
        const long base = (long)w * 1024 + lane * 4;
        const float* pa = a_bytes + base;
        const float* pb = b_bytes + base;

        // Issue all 8 loads up front (independent, 1 KiB/instr coalesced).
        const f32x4 a0 = *(const f32x4*)(pa);
        const f32x4 a1 = *(const f32x4*)(pa + 256);
        const f32x4 a2 = *(const f32x4*)(pa + 512);
        const f32x4 a3 = *(const f32x4*)(pa + 768);
        const f32x4 b0 = *(const f32x4*)(pb);
        const f32x4 b1 = *(const f32x4*)(pb + 256);
        const f32x4 b2 = *(const f32x4*)(pb + 512);
        const f32x4 b3 = *(const f32x4*)(pb + 768);

        // Index of the single 1.0 within a 256-float chunk, via 4 ballots.
        // Exactly one mask is nonzero; index = 4*lane_of_hit + component.
        auto idx_of = [&](const f32x4 v) -> uint32_t {
            const uint64_t m0 = __ballot(v.x > 0.5f);
            const uint64_t m1 = __ballot(v.y > 0.5f);
            const uint64_t m2 = __ballot(v.z > 0.5f);
            const uint64_t m3 = __ballot(v.w > 0.5f);
            const uint64_t m  = m0 | m1 | m2 | m3;
            const uint32_t hl = (uint32_t)__ffsll((unsigned long long)m) - 1u;
            const uint32_t c  = (m1 ? 1u : 0u) | (m2 ? 2u : 0u) | (m3 ? 3u : 0u);
            return hl * 4u + c;
        };

        const uint32_t aw = idx_of(a0) | (idx_of(a1) << 8) |
                            (idx_of(a2) << 16) | (idx_of(a3) << 24);
        const uint32_t bw = idx_of(b0) | (idx_of(b1) << 8) |
                            (idx_of(b2) << 16) | (idx_of(b3) << 24);

        const uint32_t s = aw + bw;   // ripple-carry add; carry out of byte 3 dropped
        const uint32_t o = s ^ aw;    // chained per-byte XOR with operand a

        float* po = out + base;
        const int j = lane * 4;
#pragma unroll
        for (int k = 0; k < 4; ++k) {
            const int oi = (int)((o >> (8 * k)) & 255u);
            f32x4 ov;
            ov.x = (j     == oi) ? 1.0f : 0.0f;
            ov.y = (j + 1 == oi) ? 1.0f : 0.0f;
            ov.z = (j + 2 == oi) ? 1.0f : 0.0f;
            ov.w = (j + 3 == oi) ? 1.0f : 0.0f;
            // Write-only stream: nontemporal so it doesn't evict input L3 lines.
            __builtin_nontemporal_store(ov, (f32x4*)(po + k * 256));
        }
    }
}

extern "C" void kernel_launch(void* const* d_in, const int* in_sizes, int n_in,
                              void* d_out, int out_size, void* d_ws, size_t ws_size,
                              hipStream_t stream)
{
    const float* a_bytes = (const float*)d_in[0];  // [B,4,256]
    const float* b_bytes = (const float*)d_in[1];  // [B,4,256]
    float* out = (float*)d_out;                    // [B,4,256]
    const int n_words = in_sizes[0] / 1024;        // B

    // Memory-bound: cap the grid and grid-stride (8192 waves -> 8 words/wave).
    const int blocks = 2048;
    vm_kernel<<<blocks, 256, 0, stream>>>(a_bytes, b_bytes, out, n_words);
}

// Round 2
// 591.571 us; speedup vs baseline: 1.0216x; 1.0216x over previous
//
#include <hip/hip_runtime.h>
#include <stdint.h>

typedef float f32x4 __attribute__((ext_vector_type(4)));

// One WAVE per 32-bit word, full grid (no grid-stride loop): each wave issues
// its 8 KiB of loads at launch and retires after 4 stores, so the chip always
// has a deep pool of outstanding loads (wave turnover = pipelining).
// Lane l's chunk k is the float4 at word_base + k*256 + l*4 floats: every
// load/store instruction is a contiguous aligned 1 KiB across the 64 lanes,
// and chunk k == byte position k.
// Byte index extraction uses __ballot (exactly one 1.0 per 256-float chunk):
// no LDS, no __syncthreads, no shuffle chains; word arithmetic is SALU.
__global__ __launch_bounds__(256) void vm_kernel(
    const float* __restrict__ a_bytes,
    const float* __restrict__ b_bytes,
    float* __restrict__ out,
    int n_words)
{
    const int lane = threadIdx.x & 63;
    const int w    = blockIdx.x * 4 + (threadIdx.x >> 6);
    if (w >= n_words) return;

    const long base = (long)w * 1024 + lane * 4;
    const float* pa = a_bytes + base;
    const float* pb = b_bytes + base;

    // Issue all 8 loads up front (independent, 1 KiB/instr coalesced).
    const f32x4 a0 = *(const f32x4*)(pa);
    const f32x4 a1 = *(const f32x4*)(pa + 256);
    const f32x4 a2 = *(const f32x4*)(pa + 512);
    const f32x4 a3 = *(const f32x4*)(pa + 768);
    const f32x4 b0 = *(const f32x4*)(pb);
    const f32x4 b1 = *(const f32x4*)(pb + 256);
    const f32x4 b2 = *(const f32x4*)(pb + 512);
    const f32x4 b3 = *(const f32x4*)(pb + 768);

    // Index of the single 1.0 within a 256-float chunk, via 4 ballots.
    // Exactly one mask is nonzero; index = 4*lane_of_hit + component.
    auto idx_of = [&](const f32x4 v) -> uint32_t {
        const uint64_t m0 = __ballot(v.x > 0.5f);
        const uint64_t m1 = __ballot(v.y > 0.5f);
        const uint64_t m2 = __ballot(v.z > 0.5f);
        const uint64_t m3 = __ballot(v.w > 0.5f);
        const uint64_t m  = m0 | m1 | m2 | m3;
        const uint32_t hl = (uint32_t)__ffsll((unsigned long long)m) - 1u;
        const uint32_t c  = (m1 ? 1u : 0u) | (m2 ? 2u : 0u) | (m3 ? 3u : 0u);
        return hl * 4u + c;
    };

    const uint32_t aw = idx_of(a0) | (idx_of(a1) << 8) |
                        (idx_of(a2) << 16) | (idx_of(a3) << 24);
    const uint32_t bw = idx_of(b0) | (idx_of(b1) << 8) |
                        (idx_of(b2) << 16) | (idx_of(b3) << 24);

    const uint32_t s = aw + bw;   // ripple-carry add; carry out of byte 3 dropped
    const uint32_t o = s ^ aw;    // chained per-byte XOR with operand a

    float* po = out + base;
    const int j = lane * 4;
#pragma unroll
    for (int k = 0; k < 4; ++k) {
        const int oi = (int)((o >> (8 * k)) & 255u);
        f32x4 ov;
        ov.x = (j     == oi) ? 1.0f : 0.0f;
        ov.y = (j + 1 == oi) ? 1.0f : 0.0f;
        ov.z = (j + 2 == oi) ? 1.0f : 0.0f;
        ov.w = (j + 3 == oi) ? 1.0f : 0.0f;
        *(f32x4*)(po + k * 256) = ov;
    }
}

extern "C" void kernel_launch(void* const* d_in, const int* in_sizes, int n_in,
                              void* d_out, int out_size, void* d_ws, size_t ws_size,
                              hipStream_t stream)
{
    const float* a_bytes = (const float*)d_in[0];  // [B,4,256]
    const float* b_bytes = (const float*)d_in[1];  // [B,4,256]
    float* out = (float*)d_out;                    // [B,4,256]
    const int n_words = in_sizes[0] / 1024;        // B

    const int blocks = (n_words + 3) / 4;          // one wave (64 thr) per word
    vm_kernel<<<blocks, 256, 0, stream>>>(a_bytes, b_bytes, out, n_words);
}